// Round 1
// baseline (20.082 us; speedup 1.0000x reference)
//
#include <hip/hip_runtime.h>

// ---------------------------------------------------------------------------
// Lamm loss on MI355X.
// Levels (b=64): (100,167) (50,84) (25,42) (13,21) (7,11)
// Kernel 1: blocks [0,171) = h-level partial sums (fixed-order, deterministic)
//           blocks [171,176) = per-level rasterize+count, one block per level,
//           whole difference-grid in LDS (max 100*167 ints = 66.8 KB).
// Kernel 2: single block combines partials -> final scalar loss.
// ---------------------------------------------------------------------------

#define NBOXES 4096

// per-level geometry
__device__ __constant__ int c_LH[5] = {100, 50, 25, 13, 7};
__device__ __constant__ int c_LW[5] = {167, 84, 42, 21, 11};
__device__ __constant__ int c_LS[5] = {167, 85, 43, 21, 11};   // odd LDS stride
// float4 counts per level: 64*h*w/4
__device__ __constant__ int c_LN4[5] = {267200, 67200, 16800, 4368, 1232};
// sum-reduction blocks per level and prefix offsets
__device__ __constant__ int c_NBS[5]   = {128, 32, 8, 2, 1};
__device__ __constant__ int c_NBOFF[5] = {0, 128, 160, 168, 170};

#define NB_SUM   171
#define NB_TOTAL 176
#define WS_COV   176   // ws float index where per-level coverage counts go

__global__ __launch_bounds__(256) void k_main(
    const float* __restrict__ h0, const float* __restrict__ h1,
    const float* __restrict__ h2, const float* __restrict__ h3,
    const float* __restrict__ h4, const float* __restrict__ boxes,
    const int* __restrict__ dimx, const int* __restrict__ dimy,
    float* __restrict__ ws)
{
    __shared__ int   sgrid[16700];   // max level grid h*S = 100*167
    __shared__ float fred[256];

    const int bid = blockIdx.x;
    const int tid = threadIdx.x;

    if (bid < NB_SUM) {
        // ------------------ h-level sum reduction ------------------
        int level;
        if      (bid < 128) level = 0;
        else if (bid < 160) level = 1;
        else if (bid < 168) level = 2;
        else if (bid < 170) level = 3;
        else                level = 4;

        const float* hp = (level == 0) ? h0 :
                          (level == 1) ? h1 :
                          (level == 2) ? h2 :
                          (level == 3) ? h3 : h4;
        const int n4     = c_LN4[level];
        const int nb     = c_NBS[level];
        const int boff   = c_NBOFF[level];

        const float4* p = (const float4*)hp;
        int idx    = (bid - boff) * 256 + tid;
        int stride = nb * 256;
        float s = 0.0f;
        for (int i = idx; i < n4; i += stride) {
            float4 v = p[i];
            s += v.x + v.y + v.z + v.w;
        }
        fred[tid] = s;
        __syncthreads();
        #pragma unroll
        for (int off = 128; off > 0; off >>= 1) {
            if (tid < off) fred[tid] += fred[tid + off];
            __syncthreads();
        }
        if (tid == 0) ws[bid] = fred[0];
    } else {
        // ------------------ per-level rasterize + count ------------------
        const int level = bid - NB_SUM;
        const int h = c_LH[level];
        const int w = c_LW[level];
        const int S = c_LS[level];
        const int cells = h * S;

        for (int i = tid; i < cells; i += 256) sgrid[i] = 0;

        // scales: division correctly rounded -> identical to f32 path of ref
        const float sx = (float)((double)w / (double)dimx[0]);
        const float sy = (float)((double)h / (double)dimy[0]);
        __syncthreads();

        const float4* bx = (const float4*)boxes;
        for (int b = tid; b < NBOXES; b += 256) {
            float4 v = bx[b];
            // round (half-even, matches jnp.round) THEN clip, as reference
            int x1 = (int)fminf(fmaxf(rintf(v.x * sx), 0.0f), (float)(w - 1));
            int y1 = (int)fminf(fmaxf(rintf(v.y * sy), 0.0f), (float)(h - 1));
            int x2 = (int)fminf(fmaxf(rintf(v.z * sx), 0.0f), (float)w);
            int y2 = (int)fminf(fmaxf(rintf(v.w * sy), 0.0f), (float)h);
            bool valid = (x2 > x1) && (y2 > y1) && (x1 + x2 < w) && (y1 + y2 < h);
            if (valid) {
                atomicAdd(&sgrid[y1 * S + x1], 1);
                if (x2 < w)             atomicAdd(&sgrid[y1 * S + x2], -1);
                if (y2 < h)             atomicAdd(&sgrid[y2 * S + x1], -1);
                if (x2 < w && y2 < h)   atomicAdd(&sgrid[y2 * S + x2], 1);
            }
        }
        __syncthreads();

        // row cumsum along x (one thread per row; odd stride -> no conflicts)
        if (tid < h) {
            int run = 0;
            int base = tid * S;
            for (int x = 0; x < w; ++x) {
                run += sgrid[base + x];
                sgrid[base + x] = run;
            }
        }
        __syncthreads();

        // column cumsum + covered-cell count (one thread per column)
        int cover = 0;
        if (tid < w) {
            int run = 0;
            for (int y = 0; y < h; ++y) {
                run += sgrid[y * S + tid];
                cover += (run > 0);
            }
        }
        fred[tid] = (float)cover;
        __syncthreads();
        #pragma unroll
        for (int off = 128; off > 0; off >>= 1) {
            if (tid < off) fred[tid] += fred[tid + off];
            __syncthreads();
        }
        if (tid == 0) ws[WS_COV + level] = fred[0];
    }
}

__global__ __launch_bounds__(256) void k_final(
    const float* __restrict__ ws, float* __restrict__ out)
{
    __shared__ float fred[256];
    __shared__ float lv[5];
    const int tid = threadIdx.x;

    fred[tid] = (tid < NB_SUM) ? ws[tid] : 0.0f;
    __syncthreads();

    if (tid < 5) {
        const int off = c_NBOFF[tid];
        const int nb  = c_NBS[tid];
        float s = 0.0f;
        for (int i = 0; i < nb; ++i) s += fred[off + i];
        const float tn = (float)(64 * c_LH[tid] * c_LW[tid]);
        const float pi = ws[WS_COV + tid] / tn;
        const float d  = s / tn - pi;
        lv[tid] = d * d;
    }
    __syncthreads();
    if (tid == 0) {
        float l = ((((lv[0] + lv[1]) + lv[2]) + lv[3]) + lv[4]) / 5.0f;
        out[0] = l;
    }
}

extern "C" void kernel_launch(void* const* d_in, const int* in_sizes, int n_in,
                              void* d_out, int out_size, void* d_ws, size_t ws_size,
                              hipStream_t stream) {
    const float* h0    = (const float*)d_in[0];
    const float* h1    = (const float*)d_in[1];
    const float* h2    = (const float*)d_in[2];
    const float* h3    = (const float*)d_in[3];
    const float* h4    = (const float*)d_in[4];
    const float* boxes = (const float*)d_in[5];
    const int*   dimx  = (const int*)d_in[6];
    const int*   dimy  = (const int*)d_in[7];
    float* ws  = (float*)d_ws;
    float* out = (float*)d_out;

    k_main<<<NB_TOTAL, 256, 0, stream>>>(h0, h1, h2, h3, h4, boxes,
                                         dimx, dimy, ws);
    k_final<<<1, 256, 0, stream>>>(ws, out);
}